// Round 7
// baseline (451.712 us; speedup 1.0000x reference)
//
#include <hip/hip_runtime.h>
#include <hip/hip_bf16.h>

// ---------- problem constants ----------
constexpr int Nrows = 8192;   // batch rows
constexpr int L     = 256;    // input_len / features
constexpr int D     = 128;    // hidden per head
constexpr float EPS = 1e-5f;

typedef __bf16 bf16x8 __attribute__((ext_vector_type(8)));
typedef __bf16 bf16x4 __attribute__((ext_vector_type(4)));
typedef float  f32x4  __attribute__((ext_vector_type(4)));

#define MFMA16(a, b, c) __builtin_amdgcn_mfma_f32_16x16x32_bf16((a), (b), (c), 0, 0, 0)

// ============================================================
// fused pre-pass: param convert+transpose (blocks 0..1535) and
// bn1 column stats for x (blocks 1536..1791). stats pre-zeroed by memset.
// ============================================================
__global__ void k_pre(const float* __restrict__ x,
                      const float* __restrict__ Q, const float* __restrict__ K,
                      const float* __restrict__ Vd, const float* __restrict__ Vup,
                      const float* __restrict__ W,
                      __bf16* __restrict__ Bt, __bf16* __restrict__ VupT,
                      __bf16* __restrict__ Wb, float* __restrict__ sum,
                      float* __restrict__ sq) {
    if (blockIdx.x >= 1536) {            // bn stats: 256 blocks x 32 rows
        int col = threadIdx.x;
        int r0 = (blockIdx.x - 1536) * 32;
        float s = 0.f, s2 = 0.f;
        for (int i = 0; i < 32; i++) {
            float v = x[(r0 + i) * L + col];
            s += v; s2 += v * v;
        }
        atomicAdd(&sum[col], s);
        atomicAdd(&sq[col], s2);
        return;
    }
    int i = blockIdx.x * 256 + threadIdx.x;
    if (i < 6 * 128 * 256) {
        int g = i >> 15; int r = i & 32767; int d = r >> 8; int l = r & 255;
        const float* src = (g % 3 == 0 ? Q : (g % 3 == 1 ? K : Vd)) + (g / 3) * (L * D);
        Bt[i] = (__bf16)src[l * D + d];
    } else if (i < 8 * 128 * 256) {
        int j = i - 6 * 128 * 256;
        int h = j >> 15; int r = j & 32767; int l = r >> 7; int d = r & 127;
        VupT[j] = (__bf16)Vup[h * (D * L) + d * L + l];
    } else {
        int j = i - 8 * 128 * 256;
        Wb[j] = (__bf16)W[j];
    }
}

// ============================================================
// bn1 normalize: x (fp32) -> hb (bf16), 8 elems/thread
// ============================================================
__global__ void k_bn_norm1(const float* __restrict__ x, const float* __restrict__ sum,
                           const float* __restrict__ sq, __bf16* __restrict__ hb) {
    int i = (blockIdx.x * 256 + threadIdx.x) * 8;
    int col = i & (L - 1);
    f32x4 v0 = *(const f32x4*)(x + i);
    f32x4 v1 = *(const f32x4*)(x + i + 4);
    bf16x8 o;
#pragma unroll
    for (int j = 0; j < 8; j++) {
        float vv = j < 4 ? v0[j] : v1[j - 4];
        float m   = sum[col + j] * (1.0f / Nrows);
        float var = sq[col + j] * (1.0f / Nrows) - m * m;
        float rs  = rsqrtf(var + EPS);
        o[j] = (__bf16)((vv - m) * rs);
    }
    *(bf16x8*)(hb + i) = o;
}

// ============================================================
// QKV projection: 64-row M-tiles (grid 128x6), wave = 16 rows.
// q/k row-major [8192][128]; v repacked via LDS -> Vt[head][128][8192]
// ============================================================
__launch_bounds__(256)
__global__ void k_gemm_qkv(const __bf16* __restrict__ h, const __bf16* __restrict__ Bt,
                           __bf16* __restrict__ q0, __bf16* __restrict__ k0,
                           __bf16* __restrict__ q1, __bf16* __restrict__ k1,
                           __bf16* __restrict__ Vt) {
    __shared__ __bf16 lv[64][130];
    int g = blockIdx.y;
    int m0 = blockIdx.x * 64;
    int w = threadIdx.x >> 6, lane = threadIdx.x & 63;
    int c = lane & 15, qd = lane >> 4;
    int mw = m0 + w * 16;
    const __bf16* B = Bt + g * (128 * 256);

    f32x4 acc[8] = {};
#pragma unroll
    for (int kc = 0; kc < 8; kc++) {
        bf16x8 a = *(const bf16x8*)(h + (mw + c) * L + kc * 32 + qd * 8);
#pragma unroll
        for (int nt = 0; nt < 8; nt++) {
            bf16x8 b = *(const bf16x8*)(B + (nt * 16 + c) * L + kc * 32 + qd * 8);
            acc[nt] = MFMA16(a, b, acc[nt]);
        }
    }
    if (g == 2 || g == 5) {
#pragma unroll
        for (int nt = 0; nt < 8; nt++)
#pragma unroll
            for (int r = 0; r < 4; r++)
                lv[w * 16 + 4 * qd + r][nt * 16 + c] = (__bf16)acc[nt][r];
        __syncthreads();
        __bf16* vt = Vt + (g / 3) * (128 * Nrows);
        int t = threadIdx.x;
        int d = t >> 1, nb = (t & 1) * 32;
#pragma unroll
        for (int j = 0; j < 4; j++) {
            bf16x8 o;
#pragma unroll
            for (int e = 0; e < 8; e++) o[e] = lv[nb + j * 8 + e][d];
            *(bf16x8*)(vt + d * Nrows + m0 + nb + j * 8) = o;
        }
    } else {
        __bf16* dst = (g == 0) ? q0 : (g == 1) ? k0 : (g == 3) ? q1 : k1;
#pragma unroll
        for (int nt = 0; nt < 8; nt++)
#pragma unroll
            for (int r = 0; r < 4; r++)
                dst[(mw + 4 * qd + r) * D + nt * 16 + c] = (__bf16)acc[nt][r];
    }
}

// ============================================================
// Flash attention (no-max online softmax: logits bounded |s|<~13).
// L2-BW-bound analysis: every config lands at bytes/(8 XCD x ~1 TB/s);
// bytes = nblocks x 4MB(K+Vt per head). So: 128 blocks x 128 Q-rows
// -> 0.5 GB. head = blockIdx&1 == XCD parity (blocks on XCD x all have
// blockIdx===x mod 8 -> single head per XCD L2).
// 512 thr = 8 waves = 2 row-groups(g) x 4 slices(u). Per 128-key step:
//   QK: wave (g,u) = rows g*64, keys u*32 -> P (shared LDS) + partial l
//   barrier; PV: wave (g,u) = rows g*64, dv u*32 (oacc only 4x2=32 AGPR)
//   barrier. Peak regs ~225 <= 256 -> 2 waves/SIMD, no spills.
// Each wave owns a disjoint O slice -> direct epilogue, no combine.
// ============================================================
__launch_bounds__(512, 2)
__global__ void k_flash(const __bf16* __restrict__ q0, const __bf16* __restrict__ k0,
                        const __bf16* __restrict__ q1, const __bf16* __restrict__ k1,
                        const __bf16* __restrict__ Vt, __bf16* __restrict__ O) {
    int head = blockIdx.x & 1;
    int qtile = blockIdx.x >> 1;       // 0..63
    int m0 = qtile * 128;
    const __bf16* qm = head ? q1 : q0;
    const __bf16* km = head ? k1 : k0;
    const __bf16* vt = Vt + head * (128 * Nrows);
    __bf16* Og = O + head * (Nrows * D);

    int tid = threadIdx.x;
    int w = tid >> 6, lane = tid & 63;
    int g = w >> 2, u = w & 3;         // row-group, key/dv slice
    int c = lane & 15, qd = lane >> 4;

    __shared__ __bf16 Psh[128][136];   // 34.8 KB shared P
    __shared__ float l_red[8][64];
    __shared__ float l_inv[128];

    bf16x8 aq[4][4];
#pragma unroll
    for (int mt = 0; mt < 4; mt++)
#pragma unroll
        for (int kc = 0; kc < 4; kc++)
            aq[mt][kc] = *(const bf16x8*)(qm + (m0 + g * 64 + mt * 16 + c) * D + kc * 32 + qd * 8);

    f32x4 oacc[4][2] = {};
    float lp[4][4] = {};

    for (int n0 = 0; n0 < Nrows; n0 += 128) {
        // prefetch PV B-frags for this wave's 32-dv slice (independent of QK)
        bf16x8 vb[8];
#pragma unroll
        for (int dvt = 0; dvt < 2; dvt++)
#pragma unroll
            for (int kf = 0; kf < 4; kf++)
                vb[dvt * 4 + kf] = *(const bf16x8*)(vt + (u * 32 + dvt * 16 + c) * Nrows +
                                                    n0 + kf * 32 + qd * 8);
        // K frags for this wave's 32-key slice
        int nb = n0 + u * 32;
        bf16x8 kb[2][4];
#pragma unroll
        for (int nt = 0; nt < 2; nt++)
#pragma unroll
            for (int kc = 0; kc < 4; kc++)
                kb[nt][kc] = *(const bf16x8*)(km + (nb + nt * 16 + c) * D + kc * 32 + qd * 8);

        // QK + exp -> shared P
#pragma unroll
        for (int nt = 0; nt < 2; nt++) {
            f32x4 s[4] = {};
#pragma unroll
            for (int kc = 0; kc < 4; kc++)
#pragma unroll
                for (int mt = 0; mt < 4; mt++) s[mt] = MFMA16(aq[mt][kc], kb[nt][kc], s[mt]);
#pragma unroll
            for (int mt = 0; mt < 4; mt++)
#pragma unroll
                for (int r = 0; r < 4; r++) {
                    float e = __expf(s[mt][r]);
                    lp[mt][r] += e;
                    Psh[g * 64 + mt * 16 + 4 * qd + r][u * 32 + nt * 16 + c] = (__bf16)e;
                }
        }
        __syncthreads();   // P complete
        // PV over all 128 keys for this wave's rows x dv-slice
#pragma unroll
        for (int kf = 0; kf < 4; kf++) {
            bf16x8 ap[4];
#pragma unroll
            for (int mt = 0; mt < 4; mt++)
                ap[mt] = *(const bf16x8*)(&Psh[g * 64 + mt * 16 + c][kf * 32 + qd * 8]);
#pragma unroll
            for (int mt = 0; mt < 4; mt++) {
                oacc[mt][0] = MFMA16(ap[mt], vb[kf], oacc[mt][0]);
                oacc[mt][1] = MFMA16(ap[mt], vb[4 + kf], oacc[mt][1]);
            }
        }
        __syncthreads();   // PV reads done before next step's P writes
    }

    // l: per-wave row sums over its key slice, then combine 4 slices
#pragma unroll
    for (int mt = 0; mt < 4; mt++)
#pragma unroll
        for (int r = 0; r < 4; r++) {
            float v = lp[mt][r];
            v += __shfl_xor(v, 1, 16);
            v += __shfl_xor(v, 2, 16);
            v += __shfl_xor(v, 4, 16);
            v += __shfl_xor(v, 8, 16);
            lp[mt][r] = v;
        }
    if (c == 0) {
#pragma unroll
        for (int mt = 0; mt < 4; mt++)
#pragma unroll
            for (int r = 0; r < 4; r++)
                l_red[w][mt * 16 + 4 * qd + r] = lp[mt][r];
    }
    __syncthreads();
    if (tid < 128) {
        int gg = tid >> 6, rl = tid & 63;
        l_inv[tid] = 1.0f / (l_red[gg * 4 + 0][rl] + l_red[gg * 4 + 1][rl] +
                             l_red[gg * 4 + 2][rl] + l_red[gg * 4 + 3][rl]);
    }
    __syncthreads();

    // epilogue: wave (g,u) owns rows g*64.. x dv u*32.. -> direct write
#pragma unroll
    for (int mt = 0; mt < 4; mt++)
#pragma unroll
        for (int dvt = 0; dvt < 2; dvt++)
#pragma unroll
            for (int r = 0; r < 4; r++) {
                int row = g * 64 + mt * 16 + 4 * qd + r;
                int col = u * 32 + dvt * 16 + c;
                Og[(m0 + row) * D + col] = (__bf16)(oacc[mt][dvt][r] * l_inv[row]);
            }
}

// ============================================================
// z = hb + O0 @ Vup0 + O1 @ Vup1  (fp32 out) + FUSED bn2 column stats
// grid (128, 2): 64-row x 128-col tiles
// ============================================================
__launch_bounds__(256)
__global__ void k_gemm_vup(const __bf16* __restrict__ O, const __bf16* __restrict__ VupT,
                           const __bf16* __restrict__ hb, float* __restrict__ z,
                           float* __restrict__ sum2, float* __restrict__ sq2) {
    __shared__ float colsum[128], colsq[128];
    int n0 = blockIdx.y * 128;
    int m0 = blockIdx.x * 64;
    int tid = threadIdx.x;
    int w = tid >> 6, lane = tid & 63;
    int c = lane & 15, qd = lane >> 4;
    int mw = m0 + w * 16;
    if (tid < 128) { colsum[tid] = 0.f; colsq[tid] = 0.f; }
    __syncthreads();

    f32x4 acc[8] = {};
#pragma unroll
    for (int kc = 0; kc < 8; kc++) {
        const __bf16* Oh = O + (kc >> 2) * (Nrows * D);
        const __bf16* Vh = VupT + (kc >> 2) * (L * D);
        int ko = (kc & 3) * 32 + qd * 8;
        bf16x8 a = *(const bf16x8*)(Oh + (mw + c) * D + ko);
#pragma unroll
        for (int nt = 0; nt < 8; nt++) {
            bf16x8 b = *(const bf16x8*)(Vh + (n0 + nt * 16 + c) * D + ko);
            acc[nt] = MFMA16(a, b, acc[nt]);
        }
    }
#pragma unroll
    for (int nt = 0; nt < 8; nt++) {
        float s = 0.f, s2 = 0.f;
#pragma unroll
        for (int r = 0; r < 4; r++) {
            int row = mw + 4 * qd + r;
            int col = n0 + nt * 16 + c;
            float v = acc[nt][r] + (float)hb[row * L + col];
            z[row * L + col] = v;
            s += v; s2 += v * v;
        }
        s  += __shfl_xor(s, 16);  s  += __shfl_xor(s, 32);
        s2 += __shfl_xor(s2, 16); s2 += __shfl_xor(s2, 32);
        if (qd == 0) {
            atomicAdd(&colsum[nt * 16 + c], s);
            atomicAdd(&colsq[nt * 16 + c], s2);
        }
    }
    __syncthreads();
    if (tid < 128) {
        atomicAdd(&sum2[n0 + tid], colsum[tid]);
        atomicAdd(&sq2[n0 + tid], colsq[tid]);
    }
}

// ============================================================
// layer 1: out = relu(bn2(z) @ W0^T + b0) -> h3 (bf16)
// bn2 applied inline to the fp32 A operand (m/rs precomputed in LDS).
// grid 128 (64 rows/block), full 256 cols per block.
// ============================================================
__launch_bounds__(256)
__global__ void k_gemm_w1(const float* __restrict__ z, const float* __restrict__ sum2,
                          const float* __restrict__ sq2, const __bf16* __restrict__ W,
                          const float* __restrict__ bias, __bf16* __restrict__ out) {
    __shared__ float mS[256], rS[256];
    int tid = threadIdx.x;
    {
        float m = sum2[tid] * (1.0f / Nrows);
        float var = sq2[tid] * (1.0f / Nrows) - m * m;
        mS[tid] = m; rS[tid] = rsqrtf(var + EPS);
    }
    __syncthreads();
    int m0 = blockIdx.x * 64;
    int w = tid >> 6, lane = tid & 63;
    int c = lane & 15, qd = lane >> 4;
    int mw = m0 + w * 16;

    f32x4 acc[16] = {};
#pragma unroll
    for (int kc = 0; kc < 8; kc++) {
        int ko = kc * 32 + qd * 8;
        f32x4 z0 = *(const f32x4*)(z + (mw + c) * L + ko);
        f32x4 z1 = *(const f32x4*)(z + (mw + c) * L + ko + 4);
        bf16x8 a;
#pragma unroll
        for (int j = 0; j < 4; j++) {
            a[j]     = (__bf16)((z0[j] - mS[ko + j]) * rS[ko + j]);
            a[j + 4] = (__bf16)((z1[j] - mS[ko + 4 + j]) * rS[ko + 4 + j]);
        }
#pragma unroll
        for (int nt = 0; nt < 16; nt++) {
            bf16x8 b = *(const bf16x8*)(W + (nt * 16 + c) * L + ko);
            acc[nt] = MFMA16(a, b, acc[nt]);
        }
    }
#pragma unroll
    for (int nt = 0; nt < 16; nt++) {
        int col = nt * 16 + c;
        float bv = bias[col];
#pragma unroll
        for (int r = 0; r < 4; r++) {
            int row = mw + 4 * qd + r;
            out[row * L + col] = (__bf16)fmaxf(acc[nt][r] + bv, 0.0f);
        }
    }
}

// ============================================================
// layer 2: out = relu(h3 @ W1^T + b1) -> fp32 d_out
// ============================================================
__launch_bounds__(256)
__global__ void k_gemm_w2(const __bf16* __restrict__ hin, const __bf16* __restrict__ W,
                          const float* __restrict__ bias, float* __restrict__ out) {
    int m0 = blockIdx.x * 64;
    int w = threadIdx.x >> 6, lane = threadIdx.x & 63;
    int c = lane & 15, qd = lane >> 4;
    int mw = m0 + w * 16;

    f32x4 acc[16] = {};
#pragma unroll
    for (int kc = 0; kc < 8; kc++) {
        int ko = kc * 32 + qd * 8;
        bf16x8 a = *(const bf16x8*)(hin + (mw + c) * L + ko);
#pragma unroll
        for (int nt = 0; nt < 16; nt++) {
            bf16x8 b = *(const bf16x8*)(W + (nt * 16 + c) * L + ko);
            acc[nt] = MFMA16(a, b, acc[nt]);
        }
    }
#pragma unroll
    for (int nt = 0; nt < 16; nt++) {
        int col = nt * 16 + c;
        float bv = bias[col];
#pragma unroll
        for (int r = 0; r < 4; r++) {
            int row = mw + 4 * qd + r;
            out[row * L + col] = fmaxf(acc[nt][r] + bv, 0.0f);
        }
    }
}

// ============================================================
extern "C" void kernel_launch(void* const* d_in, const int* in_sizes, int n_in,
                              void* d_out, int out_size, void* d_ws, size_t ws_size,
                              hipStream_t stream) {
    (void)in_sizes; (void)n_in; (void)out_size; (void)ws_size;
    const float* x   = (const float*)d_in[0];
    const float* Q   = (const float*)d_in[1];
    const float* K   = (const float*)d_in[2];
    const float* Vd  = (const float*)d_in[3];
    const float* Vup = (const float*)d_in[4];
    const float* W   = (const float*)d_in[5];
    const float* b   = (const float*)d_in[6];
    float* out = (float*)d_out;

    char* ws = (char*)d_ws;
    size_t off = 0;
    auto alloc = [&](size_t bytes) -> void* {
        void* p = ws + off;
        off += (bytes + 255) & ~(size_t)255;
        return p;
    };
    float*  stats = (float*)alloc(4 * 256 * sizeof(float)); // sum1,sq1,sum2,sq2
    __bf16* Bt    = (__bf16*)alloc(6 * 128 * 256 * 2);
    __bf16* VupT  = (__bf16*)alloc(2 * 256 * 128 * 2);
    __bf16* Wb    = (__bf16*)alloc(2 * 256 * 256 * 2);
    __bf16* hb    = (__bf16*)alloc((size_t)Nrows * L * 2);
    __bf16* q0    = (__bf16*)alloc((size_t)Nrows * D * 2);
    __bf16* k0    = (__bf16*)alloc((size_t)Nrows * D * 2);
    __bf16* q1    = (__bf16*)alloc((size_t)Nrows * D * 2);
    __bf16* k1    = (__bf16*)alloc((size_t)Nrows * D * 2);
    __bf16* Vt    = (__bf16*)alloc((size_t)2 * 128 * Nrows * 2);
    __bf16* O     = (__bf16*)alloc((size_t)2 * Nrows * D * 2);
    float*  z     = (float*)alloc((size_t)Nrows * L * 4);
    __bf16* h3    = (__bf16*)alloc((size_t)Nrows * L * 2);

    float* sum1 = stats, *sq1 = stats + 256, *sum2 = stats + 512, *sq2 = stats + 768;

    hipMemsetAsync(stats, 0, 4 * 256 * sizeof(float), stream);
    k_pre<<<1792, 256, 0, stream>>>(x, Q, K, Vd, Vup, W, Bt, VupT, Wb, sum1, sq1);
    k_bn_norm1<<<1024, 256, 0, stream>>>(x, sum1, sq1, hb);
    k_gemm_qkv<<<dim3(128, 6), 256, 0, stream>>>(hb, Bt, q0, k0, q1, k1, Vt);
    k_flash<<<128, 512, 0, stream>>>(q0, k0, q1, k1, Vt, O);
    k_gemm_vup<<<dim3(128, 2), 256, 0, stream>>>(O, VupT, hb, z, sum2, sq2);
    k_gemm_w1<<<128, 256, 0, stream>>>(z, sum2, sq2, Wb, b, h3);
    k_gemm_w2<<<128, 256, 0, stream>>>(h3, Wb + 256 * 256, b + 256, out);
}